// Round 1
// baseline (406.902 us; speedup 1.0000x reference)
//
#include <hip/hip_runtime.h>
#include <cstddef>
#include <cstdint>

// Problem constants (match reference)
#define BB 16
#define NN 33600
#define CC 80
#define MAXN 100
#define NBINS 4096
#define MAXC 1024
#define SCORE_THR_F 0.05f
#define IOU_THR_F 0.65f

__device__ __forceinline__ float sigmoidf_acc(float x) {
  // accurate sigmoid: 1/(1+exp(-x)); expf is ~1ulp, matches np/jax closely
  return 1.0f / (1.0f + expf(-x));
}

// K1: per (b,n) compute masked score = sigmoid(max_c cls) * sigmoid(obj), -inf if below thr
__global__ __launch_bounds__(256) void k1_score(const float* __restrict__ cls,
                                                const float* __restrict__ obj,
                                                float* __restrict__ masked) {
  int gid = blockIdx.x * 256 + threadIdx.x;
  if (gid >= BB * NN) return;
  const float4* row = (const float4*)(cls + (size_t)gid * CC);
  float m = -INFINITY;
#pragma unroll
  for (int j = 0; j < CC / 4; j++) {
    float4 v = row[j];
    m = fmaxf(m, fmaxf(fmaxf(v.x, v.y), fmaxf(v.z, v.w)));
  }
  float s = sigmoidf_acc(m) * sigmoidf_acc(obj[gid]);
  masked[gid] = (s >= SCORE_THR_F) ? s : -INFINITY;
}

__device__ __forceinline__ bool kv_before(float sa, int ia, float sb, int ib) {
  // descending score; ties -> ascending original index (stable argsort semantics)
  return (sa > sb) || (sa == sb && ia < ib);
}

// K2: one block per batch. Histogram-select top-100, decode boxes, greedy NMS, write output.
__global__ __launch_bounds__(256) void k2_select_nms(const float* __restrict__ cls,
                                                     const float* __restrict__ bbox,
                                                     const float* __restrict__ priors,
                                                     const float* __restrict__ masked,
                                                     float* __restrict__ out) {
  const int b = blockIdx.x;
  const int tid = threadIdx.x;

  __shared__ int hist[NBINS];
  __shared__ float cs[MAXC];
  __shared__ int ci[MAXC];
  __shared__ int s_cnt, s_bin;
  __shared__ float bx1[MAXN], by1[MAXN], bx2[MAXN], by2[MAXN], ssc[MAXN];
  __shared__ int slab[MAXN], skeep[MAXN];

  const float* msc = masked + (size_t)b * NN;

  for (int i = tid; i < NBINS; i += 256) hist[i] = 0;
  if (tid == 0) s_cnt = 0;
  __syncthreads();

  // Pass 1: histogram of valid scores
  for (int i = tid; i < NN; i += 256) {
    float s = msc[i];
    if (s >= SCORE_THR_F) {
      int bin = min(NBINS - 1, (int)(s * (float)NBINS));
      atomicAdd(&hist[bin], 1);
    }
  }
  __syncthreads();

  // Find largest bin t with suffix count >= MAXN (t=0 if fewer than MAXN valid)
  if (tid == 0) {
    int cum = 0, t = 0;
    for (int i = NBINS - 1; i >= 0; i--) {
      cum += hist[i];
      if (cum >= MAXN) { t = i; break; }
    }
    s_bin = t;
  }
  __syncthreads();
  const int t = s_bin;

  // Pass 2: compact candidates with bin >= t
  for (int i = tid; i < NN; i += 256) {
    float s = msc[i];
    if (s >= SCORE_THR_F) {
      int bin = min(NBINS - 1, (int)(s * (float)NBINS));
      if (bin >= t) {
        int pos = atomicAdd(&s_cnt, 1);
        if (pos < MAXC) { cs[pos] = s; ci[pos] = i; }
      }
    }
  }
  __syncthreads();

  const int C = min(s_cnt, MAXC);
  for (int i = C + tid; i < MAXC; i += 256) { cs[i] = -INFINITY; ci[i] = 0x7fffffff; }
  __syncthreads();

  // Bitonic sort MAXC slots: descending score, ascending index on ties.
  for (int k = 2; k <= MAXC; k <<= 1) {
    for (int j = k >> 1; j > 0; j >>= 1) {
      for (int i = tid; i < MAXC; i += 256) {
        int ixj = i ^ j;
        if (ixj > i) {
          bool up = ((i & k) == 0);
          float si = cs[i], sj = cs[ixj];
          int ii = ci[i], ij = ci[ixj];
          bool dosw = up ? kv_before(sj, ij, si, ii) : kv_before(si, ii, sj, ij);
          if (dosw) { cs[i] = sj; cs[ixj] = si; ci[i] = ij; ci[ixj] = ii; }
        }
      }
      __syncthreads();
    }
  }

  // Materialize top-100: label (argmax over classes) + decoded box
  const int S = min(C, MAXN);
  for (int k = tid; k < MAXN; k += 256) {
    if (k < S) {
      int idx = ci[k];
      const float* crow = cls + ((size_t)b * NN + idx) * CC;
      float m = crow[0];
      int lab = 0;
      for (int c = 1; c < CC; c++) {
        float v = crow[c];
        if (v > m) { m = v; lab = c; }  // first occurrence on ties, like jnp.argmax
      }
      float4 p = ((const float4*)priors)[idx];                  // [x*s, y*s, s, s]
      float4 d = ((const float4*)bbox)[(size_t)b * NN + idx];   // [dx, dy, dw, dh]
      float cx = d.x * p.z + p.x;
      float cy = d.y * p.w + p.y;
      float hw = expf(d.z) * p.z * 0.5f;
      float hh = expf(d.w) * p.w * 0.5f;
      bx1[k] = cx - hw; by1[k] = cy - hh;
      bx2[k] = cx + hw; by2[k] = cy + hh;
      ssc[k] = cs[k];
      slab[k] = lab;
      skeep[k] = 1;  // all candidates are valid by construction
    } else {
      bx1[k] = 0.f; by1[k] = 0.f; bx2[k] = 0.f; by2[k] = 0.f;
      ssc[k] = 0.f; slab[k] = -1; skeep[k] = 0;
    }
  }
  __syncthreads();

  // Greedy class-aware NMS (sequential over i, parallel over j)
  for (int i = 0; i < MAXN - 1; i++) {
    if (skeep[i]) {
      float xi1 = bx1[i], yi1 = by1[i], xi2 = bx2[i], yi2 = by2[i];
      float ai = (xi2 - xi1) * (yi2 - yi1);
      int li = slab[i];
      for (int j = i + 1 + tid; j < MAXN; j += 256) {
        if (skeep[j] && slab[j] == li) {
          float xx1 = fmaxf(xi1, bx1[j]);
          float yy1 = fmaxf(yi1, by1[j]);
          float xx2 = fminf(xi2, bx2[j]);
          float yy2 = fminf(yi2, by2[j]);
          float inter = fmaxf(xx2 - xx1, 0.f) * fmaxf(yy2 - yy1, 0.f);
          float aj = (bx2[j] - bx1[j]) * (by2[j] - by1[j]);
          float iou = inter / (ai + aj - inter + 1e-8f);
          if (iou >= IOU_THR_F) skeep[j] = 0;
        }
      }
    }
    __syncthreads();
  }

  // Write output: dets [B,100,6] then keep [B,100] as 0.0/1.0
  for (int k = tid; k < MAXN; k += 256) {
    float* row = out + ((size_t)b * MAXN + k) * 6;
    if (skeep[k]) {
      row[0] = bx1[k]; row[1] = by1[k]; row[2] = bx2[k]; row[3] = by2[k];
      row[4] = ssc[k]; row[5] = (float)slab[k];
    } else {
      row[0] = 0.f; row[1] = 0.f; row[2] = 0.f; row[3] = 0.f;
      row[4] = 0.f; row[5] = -1.f;
    }
    out[(size_t)BB * MAXN * 6 + (size_t)b * MAXN + k] = skeep[k] ? 1.0f : 0.0f;
  }
}

extern "C" void kernel_launch(void* const* d_in, const int* in_sizes, int n_in,
                              void* d_out, int out_size, void* d_ws, size_t ws_size,
                              hipStream_t stream) {
  const float* cls    = (const float*)d_in[0];  // [B,N,C]
  const float* bbox   = (const float*)d_in[1];  // [B,N,4]
  const float* obj    = (const float*)d_in[2];  // [B,N]
  const float* priors = (const float*)d_in[3];  // [N,4]
  float* out = (float*)d_out;                   // [B,100,6] ++ [B,100]
  float* masked = (float*)d_ws;                 // [B,N] masked scores (2.15 MB)

  const int total = BB * NN;
  k1_score<<<(total + 255) / 256, 256, 0, stream>>>(cls, obj, masked);
  k2_select_nms<<<BB, 256, 0, stream>>>(cls, bbox, priors, masked, out);
}

// Round 2
// 330.773 us; speedup vs baseline: 1.2302x; 1.2302x over previous
//
#include <hip/hip_runtime.h>
#include <cstddef>
#include <cstdint>

// Problem constants (match reference)
#define BB 16
#define NN 33600
#define CC 80
#define MAXN 100
#define NBINS 4096
#define MAXC 1024
#define SCORE_THR_F 0.05f
#define IOU_THR_F 0.65f

// ws layout (bytes); total ~3.46 MB
#define OFF_MASKED 0                                  // B*N float
#define OFF_GBUF   (BB * NN * 4)                      // B*MAXC float2
#define OFF_GHIST  (OFF_GBUF + BB * MAXC * 8)         // B*NBINS int
#define OFF_T      (OFF_GHIST + BB * NBINS * 4)       // B int (padded to 64B)
#define OFF_GCOUNT (OFF_T + 64)                       // B int (padded to 64B)
#define OFF_LAB    (OFF_GCOUNT + 64)                  // B*N ushort

#define NZERO (BB * NBINS + 32)  // ghist + t + gcount ints (contiguous)

__global__ __launch_bounds__(256) void k0_zero(int* p) {
  int i = blockIdx.x * 256 + threadIdx.x;
  if (i < NZERO) p[i] = 0;
}

// K1: 4 threads per row. Score = sigmoid(max_c)*sigmoid(obj); store masked score,
// label, and build per-batch global histogram.
__global__ __launch_bounds__(256) void k1_score(const float* __restrict__ cls,
                                                const float* __restrict__ obj,
                                                float* __restrict__ masked,
                                                unsigned short* __restrict__ lab,
                                                int* __restrict__ ghist) {
  const int b = blockIdx.y;
  const int n = blockIdx.x * 64 + (threadIdx.x >> 2);  // 525*64 == 33600 exactly
  const int q = threadIdx.x & 3;
  const float4* row = (const float4*)(cls + ((size_t)b * NN + n) * CC);
  float m = -INFINITY;
  int mc = 0;
#pragma unroll
  for (int j = 0; j < 5; j++) {
    float4 v = row[q + 4 * j];
    int c0 = 4 * (q + 4 * j);
    if (v.x > m) { m = v.x; mc = c0; }
    if (v.y > m) { m = v.y; mc = c0 + 1; }
    if (v.z > m) { m = v.z; mc = c0 + 2; }
    if (v.w > m) { m = v.w; mc = c0 + 3; }
  }
  // quad butterfly reduce: (max, argmax) with lowest class index on ties
#pragma unroll
  for (int d = 1; d < 4; d <<= 1) {
    float m2 = __shfl_xor(m, d, 4);
    int c2 = __shfl_xor(mc, d, 4);
    if (m2 > m || (m2 == m && c2 < mc)) { m = m2; mc = c2; }
  }
  if (q == 0) {
    float o = obj[(size_t)b * NN + n];
    float s = (1.0f / (1.0f + expf(-m))) * (1.0f / (1.0f + expf(-o)));
    bool valid = (s >= SCORE_THR_F);
    masked[(size_t)b * NN + n] = valid ? s : -INFINITY;
    lab[(size_t)b * NN + n] = (unsigned short)mc;
    if (valid) {
      int bin = min(NBINS - 1, (int)(s * (float)NBINS));
      atomicAdd(&ghist[b * NBINS + bin], 1);
    }
  }
}

// K2: one block per batch — parallel suffix scan over histogram, find largest t
// with suffix(t) >= MAXN (t=0 if fewer than MAXN valid). Also zero gcount.
__global__ __launch_bounds__(256) void k2_thresh(const int* __restrict__ ghist,
                                                 int* __restrict__ tthr,
                                                 int* __restrict__ gcount) {
  const int b = blockIdx.x;
  const int tid = threadIdx.x;
  __shared__ int h[NBINS];
  __shared__ int sfx[256];
  __shared__ int s_t;
  for (int i = tid; i < NBINS; i += 256) h[i] = ghist[b * NBINS + i];
  if (tid == 0) s_t = 0;
  __syncthreads();
  int sum = 0;
#pragma unroll
  for (int j = 0; j < 16; j++) sum += h[tid * 16 + j];
  sfx[tid] = sum;
  __syncthreads();
  // Hillis-Steele suffix scan over the 256 chunk sums
  for (int off = 1; off < 256; off <<= 1) {
    int v = sfx[tid];
    int add = (tid + off < 256) ? sfx[tid + off] : 0;
    __syncthreads();
    sfx[tid] = v + add;
    __syncthreads();
  }
  int Sc = sfx[tid];
  int Sn = (tid < 255) ? sfx[tid + 1] : 0;
  if (Sc >= MAXN && Sn < MAXN) {
    // crossing is inside chunk tid: walk its 16 bins from the top
    int running = Sn;
    for (int bin = tid * 16 + 15; bin >= tid * 16; bin--) {
      running += h[bin];
      if (running >= MAXN) { s_t = bin; break; }
    }
  }
  __syncthreads();
  if (tid == 0) {
    tthr[b] = s_t;  // stays 0 when total valid < MAXN
    gcount[b] = 0;
  }
}

// K3: full-width compaction of candidates with bin >= t[b].
__global__ __launch_bounds__(256) void k3_compact(const float* __restrict__ masked,
                                                  const int* __restrict__ tthr,
                                                  int* __restrict__ gcount,
                                                  float2* __restrict__ gbuf) {
  const int b = blockIdx.y;
  const int n = blockIdx.x * 256 + threadIdx.x;
  if (n >= NN) return;
  float s = masked[(size_t)b * NN + n];
  if (s >= SCORE_THR_F) {
    int bin = min(NBINS - 1, (int)(s * (float)NBINS));
    if (bin >= tthr[b]) {
      int pos = atomicAdd(&gcount[b], 1);
      if (pos < MAXC) gbuf[b * MAXC + pos] = make_float2(s, __int_as_float(n));
    }
  }
}

__device__ __forceinline__ bool kv_before(float sa, int ia, float sb, int ib) {
  // descending score; ties -> ascending original index (stable argsort semantics)
  return (sa > sb) || (sa == sb && ia < ib);
}

// K4: one block per batch — sort candidates, decode top-100, greedy NMS, write.
__global__ __launch_bounds__(256) void k4_sort_nms(const float* __restrict__ bbox,
                                                   const float* __restrict__ priors,
                                                   const unsigned short* __restrict__ lab,
                                                   const int* __restrict__ gcount,
                                                   const float2* __restrict__ gbuf,
                                                   float* __restrict__ out) {
  const int b = blockIdx.x;
  const int tid = threadIdx.x;
  __shared__ float cs[MAXC];
  __shared__ int ci[MAXC];
  __shared__ float bx1[MAXN], by1[MAXN], bx2[MAXN], by2[MAXN], ssc[MAXN];
  __shared__ int slab[MAXN], skeep[MAXN];

  const int C = min(gcount[b], MAXC);
  for (int i = tid; i < MAXC; i += 256) {
    if (i < C) {
      float2 kv = gbuf[b * MAXC + i];
      cs[i] = kv.x;
      ci[i] = __float_as_int(kv.y);
    } else {
      cs[i] = -INFINITY;
      ci[i] = 0x7fffffff;
    }
  }
  __syncthreads();

  // Bitonic sort MAXC slots: descending score, ascending index on ties.
  for (int k = 2; k <= MAXC; k <<= 1) {
    for (int j = k >> 1; j > 0; j >>= 1) {
      for (int i = tid; i < MAXC; i += 256) {
        int ixj = i ^ j;
        if (ixj > i) {
          bool up = ((i & k) == 0);
          float si = cs[i], sj = cs[ixj];
          int ii = ci[i], ij = ci[ixj];
          bool dosw = up ? kv_before(sj, ij, si, ii) : kv_before(si, ii, sj, ij);
          if (dosw) { cs[i] = sj; cs[ixj] = si; ci[i] = ij; ci[ixj] = ii; }
        }
      }
      __syncthreads();
    }
  }

  // Materialize top-100: label from ws + decoded box
  const int S = min(C, MAXN);
  for (int k = tid; k < MAXN; k += 256) {
    if (k < S) {
      int idx = ci[k];
      float4 p = ((const float4*)priors)[idx];                 // [x*s, y*s, s, s]
      float4 d = ((const float4*)bbox)[(size_t)b * NN + idx];  // [dx, dy, dw, dh]
      float cx = d.x * p.z + p.x;
      float cy = d.y * p.w + p.y;
      float hw = expf(d.z) * p.z * 0.5f;
      float hh = expf(d.w) * p.w * 0.5f;
      bx1[k] = cx - hw; by1[k] = cy - hh;
      bx2[k] = cx + hw; by2[k] = cy + hh;
      ssc[k] = cs[k];
      slab[k] = (int)lab[(size_t)b * NN + idx];
      skeep[k] = 1;
    } else {
      bx1[k] = 0.f; by1[k] = 0.f; bx2[k] = 0.f; by2[k] = 0.f;
      ssc[k] = 0.f; slab[k] = -1; skeep[k] = 0;
    }
  }
  __syncthreads();

  // Greedy class-aware NMS (sequential over i, parallel over j)
  for (int i = 0; i < MAXN - 1; i++) {
    if (skeep[i]) {
      float xi1 = bx1[i], yi1 = by1[i], xi2 = bx2[i], yi2 = by2[i];
      float ai = (xi2 - xi1) * (yi2 - yi1);
      int li = slab[i];
      for (int j = i + 1 + tid; j < MAXN; j += 256) {
        if (skeep[j] && slab[j] == li) {
          float xx1 = fmaxf(xi1, bx1[j]);
          float yy1 = fmaxf(yi1, by1[j]);
          float xx2 = fminf(xi2, bx2[j]);
          float yy2 = fminf(yi2, by2[j]);
          float inter = fmaxf(xx2 - xx1, 0.f) * fmaxf(yy2 - yy1, 0.f);
          float aj = (bx2[j] - bx1[j]) * (by2[j] - by1[j]);
          float iou = inter / (ai + aj - inter + 1e-8f);
          if (iou >= IOU_THR_F) skeep[j] = 0;
        }
      }
    }
    __syncthreads();
  }

  // Write output: dets [B,100,6] then keep [B,100] as 0.0/1.0
  for (int k = tid; k < MAXN; k += 256) {
    float* row = out + ((size_t)b * MAXN + k) * 6;
    if (skeep[k]) {
      row[0] = bx1[k]; row[1] = by1[k]; row[2] = bx2[k]; row[3] = by2[k];
      row[4] = ssc[k]; row[5] = (float)slab[k];
    } else {
      row[0] = 0.f; row[1] = 0.f; row[2] = 0.f; row[3] = 0.f;
      row[4] = 0.f; row[5] = -1.f;
    }
    out[(size_t)BB * MAXN * 6 + (size_t)b * MAXN + k] = skeep[k] ? 1.0f : 0.0f;
  }
}

extern "C" void kernel_launch(void* const* d_in, const int* in_sizes, int n_in,
                              void* d_out, int out_size, void* d_ws, size_t ws_size,
                              hipStream_t stream) {
  const float* cls    = (const float*)d_in[0];  // [B,N,C]
  const float* bbox   = (const float*)d_in[1];  // [B,N,4]
  const float* obj    = (const float*)d_in[2];  // [B,N]
  const float* priors = (const float*)d_in[3];  // [N,4]
  float* out = (float*)d_out;                   // [B,100,6] ++ [B,100]

  char* ws = (char*)d_ws;
  float* masked        = (float*)(ws + OFF_MASKED);
  float2* gbuf         = (float2*)(ws + OFF_GBUF);
  int* ghist           = (int*)(ws + OFF_GHIST);
  int* tthr            = (int*)(ws + OFF_T);
  int* gcount          = (int*)(ws + OFF_GCOUNT);
  unsigned short* labw = (unsigned short*)(ws + OFF_LAB);

  k0_zero<<<(NZERO + 255) / 256, 256, 0, stream>>>(ghist);
  k1_score<<<dim3(NN / 64, BB), 256, 0, stream>>>(cls, obj, masked, labw, ghist);
  k2_thresh<<<BB, 256, 0, stream>>>(ghist, tthr, gcount);
  k3_compact<<<dim3((NN + 255) / 256, BB), 256, 0, stream>>>(masked, tthr, gcount, gbuf);
  k4_sort_nms<<<BB, 256, 0, stream>>>(bbox, priors, labw, gcount, gbuf, out);
}

// Round 3
// 303.028 us; speedup vs baseline: 1.3428x; 1.0916x over previous
//
#include <hip/hip_runtime.h>
#include <cstddef>
#include <cstdint>

// Problem constants (match reference)
#define BB 16
#define NN 33600
#define CC 80
#define MAXN 100
#define NBINS 4096
#define MAXC 1024
#define SCORE_THR_F 0.05f
#define IOU_THR_F 0.65f

// K1: 4 threads per row. masked = sigmoid(max_c cls)*sigmoid(obj), -inf if < thr.
// No argmax / no histogram here — recomputed in K2 for the ~100 winners only.
__global__ __launch_bounds__(256) void k1_score(const float* __restrict__ cls,
                                                const float* __restrict__ obj,
                                                float* __restrict__ masked) {
  const int b = blockIdx.y;
  const int n = blockIdx.x * 64 + (threadIdx.x >> 2);  // 525*64 == 33600 exactly
  const int q = threadIdx.x & 3;
  const float4* row = (const float4*)(cls + ((size_t)b * NN + n) * CC);
  float m = -INFINITY;
#pragma unroll
  for (int j = 0; j < 5; j++) {
    float4 v = row[q + 4 * j];
    m = fmaxf(m, fmaxf(fmaxf(v.x, v.y), fmaxf(v.z, v.w)));
  }
#pragma unroll
  for (int d = 1; d < 4; d <<= 1) m = fmaxf(m, __shfl_xor(m, d, 4));
  if (q == 0) {
    float o = obj[(size_t)b * NN + n];
    float s = (1.0f / (1.0f + expf(-m))) * (1.0f / (1.0f + expf(-o)));
    masked[(size_t)b * NN + n] = (s >= SCORE_THR_F) ? s : -INFINITY;
  }
}

__device__ __forceinline__ int score_bin(float s) {
  return min(NBINS - 1, (int)(s * (float)NBINS));
}

// K2: one block per batch. Histogram -> threshold -> compact -> rank-select
// top-100 -> decode+label -> pairwise suppression bitmask -> greedy scan -> write.
__global__ __launch_bounds__(256) void k2_all(const float* __restrict__ cls,
                                              const float* __restrict__ bbox,
                                              const float* __restrict__ priors,
                                              const float* __restrict__ masked,
                                              float* __restrict__ out) {
  const int b = blockIdx.x;
  const int tid = threadIdx.x;

  __shared__ int hist[NBINS];
  __shared__ int sfx[256];
  __shared__ int s_t, s_cnt;
  __shared__ float cs[MAXC];
  __shared__ int ci[MAXC];
  __shared__ int sel[MAXN];               // original anchor index, -1 if empty
  __shared__ float sb[MAXN][4];           // x1,y1,x2,y2
  __shared__ float ssc[MAXN];
  __shared__ int slab[MAXN];
  __shared__ unsigned int sup[MAXN][4];   // suppression bitmask (j bits), j>i only
  __shared__ unsigned int keepw[4];

  const float4* msc4 = (const float4*)(masked + (size_t)b * NN);

  for (int i = tid; i < NBINS; i += 256) hist[i] = 0;
  if (tid == 0) { s_t = 0; s_cnt = 0; }
  __syncthreads();

  // Pass 1: LDS histogram of valid scores (float4 loads; NN/4 = 8400)
  for (int i = tid; i < NN / 4; i += 256) {
    float4 v = msc4[i];
    if (v.x >= SCORE_THR_F) atomicAdd(&hist[score_bin(v.x)], 1);
    if (v.y >= SCORE_THR_F) atomicAdd(&hist[score_bin(v.y)], 1);
    if (v.z >= SCORE_THR_F) atomicAdd(&hist[score_bin(v.z)], 1);
    if (v.w >= SCORE_THR_F) atomicAdd(&hist[score_bin(v.w)], 1);
  }
  __syncthreads();

  // Parallel suffix scan: largest bin t with suffix count >= MAXN (0 if < MAXN valid)
  int sum = 0;
#pragma unroll
  for (int j = 0; j < 16; j++) sum += hist[tid * 16 + j];
  sfx[tid] = sum;
  __syncthreads();
  for (int off = 1; off < 256; off <<= 1) {
    int v = sfx[tid];
    int add = (tid + off < 256) ? sfx[tid + off] : 0;
    __syncthreads();
    sfx[tid] = v + add;
    __syncthreads();
  }
  {
    int Sc = sfx[tid];
    int Sn = (tid < 255) ? sfx[tid + 1] : 0;
    if (Sc >= MAXN && Sn < MAXN) {
      int running = Sn;
      for (int bin = tid * 16 + 15; bin >= tid * 16; bin--) {
        running += hist[bin];
        if (running >= MAXN) { s_t = bin; break; }
      }
    }
  }
  __syncthreads();
  const int t = s_t;

  // Pass 2: compact candidates with bin >= t into LDS (masked is L2-hot now)
  for (int i = tid; i < NN / 4; i += 256) {
    float4 v = msc4[i];
    int base = i * 4;
    if (v.x >= SCORE_THR_F && score_bin(v.x) >= t) {
      int p = atomicAdd(&s_cnt, 1); if (p < MAXC) { cs[p] = v.x; ci[p] = base; }
    }
    if (v.y >= SCORE_THR_F && score_bin(v.y) >= t) {
      int p = atomicAdd(&s_cnt, 1); if (p < MAXC) { cs[p] = v.y; ci[p] = base + 1; }
    }
    if (v.z >= SCORE_THR_F && score_bin(v.z) >= t) {
      int p = atomicAdd(&s_cnt, 1); if (p < MAXC) { cs[p] = v.z; ci[p] = base + 2; }
    }
    if (v.w >= SCORE_THR_F && score_bin(v.w) >= t) {
      int p = atomicAdd(&s_cnt, 1); if (p < MAXC) { cs[p] = v.w; ci[p] = base + 3; }
    }
  }
  __syncthreads();
  const int C = min(s_cnt, MAXC);

  for (int k = tid; k < MAXN; k += 256) sel[k] = -1;
  __syncthreads();

  // Rank by counting: rank = #{j : (s_j,i_j) before (s_i,i_i)}; ranks are unique
  // (descending score, ascending index on ties — stable argsort semantics).
  for (int i = tid; i < C; i += 256) {
    float si = cs[i]; int ii = ci[i];
    int r = 0;
    for (int j = 0; j < C; j++) {
      float sj = cs[j]; int ij = ci[j];
      r += (sj > si) || (sj == si && ij < ii);
    }
    if (r < MAXN) { sel[r] = ii; ssc[r] = si; }
  }
  __syncthreads();

  // Decode + label for the <=100 winners; zero suppression masks in parallel
  if (tid < MAXN) {
    int idx = sel[tid];
    if (idx >= 0) {
      float4 p = ((const float4*)priors)[idx];                 // [x*s, y*s, s, s]
      float4 d = ((const float4*)bbox)[(size_t)b * NN + idx];  // [dx, dy, dw, dh]
      float cx = d.x * p.z + p.x;
      float cy = d.y * p.w + p.y;
      float hw = expf(d.z) * p.z * 0.5f;
      float hh = expf(d.w) * p.w * 0.5f;
      sb[tid][0] = cx - hw; sb[tid][1] = cy - hh;
      sb[tid][2] = cx + hw; sb[tid][3] = cy + hh;
      const float4* crow = (const float4*)(cls + ((size_t)b * NN + idx) * CC);
      float m = -INFINITY; int lab = 0;
#pragma unroll 4
      for (int j = 0; j < CC / 4; j++) {
        float4 v = crow[j];
        int c0 = 4 * j;
        if (v.x > m) { m = v.x; lab = c0; }      // first occurrence on ties,
        if (v.y > m) { m = v.y; lab = c0 + 1; }  // like jnp.argmax
        if (v.z > m) { m = v.z; lab = c0 + 2; }
        if (v.w > m) { m = v.w; lab = c0 + 3; }
      }
      slab[tid] = lab;
    } else {
      sb[tid][0] = 0.f; sb[tid][1] = 0.f; sb[tid][2] = 0.f; sb[tid][3] = 0.f;
      ssc[tid] = 0.f; slab[tid] = -1;
    }
  }
  for (int i = tid; i < MAXN * 4; i += 256) ((unsigned int*)sup)[i] = 0;
  __syncthreads();

  // Pairwise IOUs -> suppression bitmask (only j > i, same label, iou >= thr)
  for (int p = tid; p < MAXN * MAXN; p += 256) {
    int i = p / MAXN, j = p % MAXN;
    if (j > i && sel[i] >= 0 && sel[j] >= 0 && slab[i] == slab[j]) {
      float xx1 = fmaxf(sb[i][0], sb[j][0]);
      float yy1 = fmaxf(sb[i][1], sb[j][1]);
      float xx2 = fminf(sb[i][2], sb[j][2]);
      float yy2 = fminf(sb[i][3], sb[j][3]);
      float inter = fmaxf(xx2 - xx1, 0.f) * fmaxf(yy2 - yy1, 0.f);
      float ai = (sb[i][2] - sb[i][0]) * (sb[i][3] - sb[i][1]);
      float aj = (sb[j][2] - sb[j][0]) * (sb[j][3] - sb[j][1]);
      float iou = inter / (ai + aj - inter + 1e-8f);
      if (iou >= IOU_THR_F) atomicOr(&sup[i][j >> 5], 1u << (j & 31));
    }
  }
  __syncthreads();

  // Greedy scan in one thread over register bitmask (~100 trivial iterations)
  if (tid == 0) {
    unsigned int kw0 = 0, kw1 = 0, kw2 = 0, kw3 = 0;
    for (int k = 0; k < MAXN; k++)
      if (sel[k] >= 0) {
        if (k < 32) kw0 |= 1u << k;
        else if (k < 64) kw1 |= 1u << (k - 32);
        else if (k < 96) kw2 |= 1u << (k - 64);
        else kw3 |= 1u << (k - 96);
      }
    for (int i = 0; i < MAXN; i++) {
      unsigned int bit = (i < 32) ? (kw0 >> i) : (i < 64) ? (kw1 >> (i - 32))
                        : (i < 96) ? (kw2 >> (i - 64)) : (kw3 >> (i - 96));
      if (bit & 1u) {
        kw0 &= ~sup[i][0]; kw1 &= ~sup[i][1];
        kw2 &= ~sup[i][2]; kw3 &= ~sup[i][3];
      }
    }
    keepw[0] = kw0; keepw[1] = kw1; keepw[2] = kw2; keepw[3] = kw3;
  }
  __syncthreads();

  // Write output: dets [B,100,6] then keep [B,100] as 0.0/1.0
  if (tid < MAXN) {
    int k = tid;
    bool kp = (keepw[k >> 5] >> (k & 31)) & 1u;
    float* row = out + ((size_t)b * MAXN + k) * 6;
    if (kp) {
      row[0] = sb[k][0]; row[1] = sb[k][1]; row[2] = sb[k][2]; row[3] = sb[k][3];
      row[4] = ssc[k];   row[5] = (float)slab[k];
    } else {
      row[0] = 0.f; row[1] = 0.f; row[2] = 0.f; row[3] = 0.f;
      row[4] = 0.f; row[5] = -1.f;
    }
    out[(size_t)BB * MAXN * 6 + (size_t)b * MAXN + k] = kp ? 1.0f : 0.0f;
  }
}

extern "C" void kernel_launch(void* const* d_in, const int* in_sizes, int n_in,
                              void* d_out, int out_size, void* d_ws, size_t ws_size,
                              hipStream_t stream) {
  const float* cls    = (const float*)d_in[0];  // [B,N,C]
  const float* bbox   = (const float*)d_in[1];  // [B,N,4]
  const float* obj    = (const float*)d_in[2];  // [B,N]
  const float* priors = (const float*)d_in[3];  // [N,4]
  float* out = (float*)d_out;                   // [B,100,6] ++ [B,100]
  float* masked = (float*)d_ws;                 // [B,N] masked scores (2.15 MB)

  k1_score<<<dim3(NN / 64, BB), 256, 0, stream>>>(cls, obj, masked);
  k2_all<<<BB, 256, 0, stream>>>(cls, bbox, priors, masked, out);
}

// Round 4
// 293.043 us; speedup vs baseline: 1.3885x; 1.0341x over previous
//
#include <hip/hip_runtime.h>
#include <cstddef>
#include <cstdint>

// Problem constants (match reference)
#define BB 16
#define NN 33600
#define CC 80
#define MAXN 100
#define NBINS 4096
#define MAXC 1024
#define SCORE_THR_F 0.05f
#define IOU_THR_F 0.65f

#define NCHUNK 525            // NN / 64
#define K1_CPB 4              // chunks per block
#define K1_GX ((NCHUNK + K1_CPB - 1) / K1_CPB)  // 132
#define K2T 512               // k2 threads

// K1: 4 threads per row, 4 row-chunks per block (fewer, fatter blocks).
// masked = sigmoid(max_c cls)*sigmoid(obj), -inf if < thr.
__global__ __launch_bounds__(256) void k1_score(const float* __restrict__ cls,
                                                const float* __restrict__ obj,
                                                float* __restrict__ masked) {
  const int b = blockIdx.y;
  const int q = threadIdx.x & 3;
  const int r = threadIdx.x >> 2;
  const int c_end = min(blockIdx.x * K1_CPB + K1_CPB, NCHUNK);
  for (int c = blockIdx.x * K1_CPB; c < c_end; c++) {
    const int n = c * 64 + r;
    const float4* row = (const float4*)(cls + ((size_t)b * NN + n) * CC);
    float m = -INFINITY;
#pragma unroll
    for (int j = 0; j < 5; j++) {
      float4 v = row[q + 4 * j];
      m = fmaxf(m, fmaxf(fmaxf(v.x, v.y), fmaxf(v.z, v.w)));
    }
#pragma unroll
    for (int d = 1; d < 4; d <<= 1) m = fmaxf(m, __shfl_xor(m, d, 4));
    if (q == 0) {
      float o = obj[(size_t)b * NN + n];
      float s = (1.0f / (1.0f + expf(-m))) * (1.0f / (1.0f + expf(-o)));
      masked[(size_t)b * NN + n] = (s >= SCORE_THR_F) ? s : -INFINITY;
    }
  }
}

__device__ __forceinline__ int score_bin(float s) {
  return min(NBINS - 1, (int)(s * (float)NBINS));
}

// K2: one block per batch. Histogram -> threshold -> compact -> rank-select
// top-100 -> decode+label -> pairwise suppression bitmask -> greedy scan -> write.
__global__ __launch_bounds__(K2T) void k2_all(const float* __restrict__ cls,
                                              const float* __restrict__ bbox,
                                              const float* __restrict__ priors,
                                              const float* __restrict__ masked,
                                              float* __restrict__ out) {
  const int b = blockIdx.x;
  const int tid = threadIdx.x;

  __shared__ int hist[NBINS];
  __shared__ int sfx[K2T];
  __shared__ int s_t, s_cnt;
  __shared__ float cs[MAXC];
  __shared__ int ci[MAXC];
  __shared__ int sel[MAXN];               // original anchor index, -1 if empty
  __shared__ float sb[MAXN][4];           // x1,y1,x2,y2
  __shared__ float ssc[MAXN];
  __shared__ int slab[MAXN];
  __shared__ unsigned int sup[MAXN][4];   // suppression bitmask (j bits), j>i only
  __shared__ unsigned int keepw[4];

  const float4* msc4 = (const float4*)(masked + (size_t)b * NN);

  for (int i = tid; i < NBINS; i += K2T) hist[i] = 0;
  if (tid == 0) { s_t = 0; s_cnt = 0; }
  __syncthreads();

  // Pass 1: LDS histogram of valid scores (float4 loads; NN/4 = 8400)
  for (int i = tid; i < NN / 4; i += K2T) {
    float4 v = msc4[i];
    if (v.x >= SCORE_THR_F) atomicAdd(&hist[score_bin(v.x)], 1);
    if (v.y >= SCORE_THR_F) atomicAdd(&hist[score_bin(v.y)], 1);
    if (v.z >= SCORE_THR_F) atomicAdd(&hist[score_bin(v.z)], 1);
    if (v.w >= SCORE_THR_F) atomicAdd(&hist[score_bin(v.w)], 1);
  }
  __syncthreads();

  // Parallel suffix scan: largest bin t with suffix count >= MAXN (0 if < MAXN valid)
  int sum = 0;
#pragma unroll
  for (int j = 0; j < NBINS / K2T; j++) sum += hist[tid * (NBINS / K2T) + j];
  sfx[tid] = sum;
  __syncthreads();
  for (int off = 1; off < K2T; off <<= 1) {
    int v = sfx[tid];
    int add = (tid + off < K2T) ? sfx[tid + off] : 0;
    __syncthreads();
    sfx[tid] = v + add;
    __syncthreads();
  }
  {
    int Sc = sfx[tid];
    int Sn = (tid < K2T - 1) ? sfx[tid + 1] : 0;
    if (Sc >= MAXN && Sn < MAXN) {
      int running = Sn;
      const int lo = tid * (NBINS / K2T);
      for (int bin = lo + (NBINS / K2T) - 1; bin >= lo; bin--) {
        running += hist[bin];
        if (running >= MAXN) { s_t = bin; break; }
      }
    }
  }
  __syncthreads();
  const int t = s_t;

  // Pass 2: compact candidates with bin >= t into LDS (masked is L2-hot now)
  for (int i = tid; i < NN / 4; i += K2T) {
    float4 v = msc4[i];
    int base = i * 4;
    if (v.x >= SCORE_THR_F && score_bin(v.x) >= t) {
      int p = atomicAdd(&s_cnt, 1); if (p < MAXC) { cs[p] = v.x; ci[p] = base; }
    }
    if (v.y >= SCORE_THR_F && score_bin(v.y) >= t) {
      int p = atomicAdd(&s_cnt, 1); if (p < MAXC) { cs[p] = v.y; ci[p] = base + 1; }
    }
    if (v.z >= SCORE_THR_F && score_bin(v.z) >= t) {
      int p = atomicAdd(&s_cnt, 1); if (p < MAXC) { cs[p] = v.z; ci[p] = base + 2; }
    }
    if (v.w >= SCORE_THR_F && score_bin(v.w) >= t) {
      int p = atomicAdd(&s_cnt, 1); if (p < MAXC) { cs[p] = v.w; ci[p] = base + 3; }
    }
  }
  __syncthreads();
  const int C = min(s_cnt, MAXC);

  for (int k = tid; k < MAXN; k += K2T) sel[k] = -1;
  __syncthreads();

  // Rank by counting: rank = #{j : (s_j,i_j) before (s_i,i_i)}; ranks are unique
  // (descending score, ascending index on ties — stable argsort semantics).
  for (int i = tid; i < C; i += K2T) {
    float si = cs[i]; int ii = ci[i];
    int r = 0;
    for (int j = 0; j < C; j++) {
      float sj = cs[j]; int ij = ci[j];
      r += (sj > si) || (sj == si && ij < ii);
    }
    if (r < MAXN) { sel[r] = ii; ssc[r] = si; }
  }
  __syncthreads();

  // Decode + label for the <=100 winners; zero suppression masks in parallel
  if (tid < MAXN) {
    int idx = sel[tid];
    if (idx >= 0) {
      float4 p = ((const float4*)priors)[idx];                 // [x*s, y*s, s, s]
      float4 d = ((const float4*)bbox)[(size_t)b * NN + idx];  // [dx, dy, dw, dh]
      float cx = d.x * p.z + p.x;
      float cy = d.y * p.w + p.y;
      float hw = expf(d.z) * p.z * 0.5f;
      float hh = expf(d.w) * p.w * 0.5f;
      sb[tid][0] = cx - hw; sb[tid][1] = cy - hh;
      sb[tid][2] = cx + hw; sb[tid][3] = cy + hh;
      const float4* crow = (const float4*)(cls + ((size_t)b * NN + idx) * CC);
      float m = -INFINITY; int lab = 0;
#pragma unroll 4
      for (int j = 0; j < CC / 4; j++) {
        float4 v = crow[j];
        int c0 = 4 * j;
        if (v.x > m) { m = v.x; lab = c0; }      // first occurrence on ties,
        if (v.y > m) { m = v.y; lab = c0 + 1; }  // like jnp.argmax
        if (v.z > m) { m = v.z; lab = c0 + 2; }
        if (v.w > m) { m = v.w; lab = c0 + 3; }
      }
      slab[tid] = lab;
    } else {
      sb[tid][0] = 0.f; sb[tid][1] = 0.f; sb[tid][2] = 0.f; sb[tid][3] = 0.f;
      ssc[tid] = 0.f; slab[tid] = -1;
    }
  }
  for (int i = tid; i < MAXN * 4; i += K2T) ((unsigned int*)sup)[i] = 0;
  __syncthreads();

  // Pairwise IOUs -> suppression bitmask (only j > i, same label, iou >= thr)
  for (int p = tid; p < MAXN * MAXN; p += K2T) {
    int i = p / MAXN, j = p % MAXN;
    if (j > i && sel[i] >= 0 && sel[j] >= 0 && slab[i] == slab[j]) {
      float xx1 = fmaxf(sb[i][0], sb[j][0]);
      float yy1 = fmaxf(sb[i][1], sb[j][1]);
      float xx2 = fminf(sb[i][2], sb[j][2]);
      float yy2 = fminf(sb[i][3], sb[j][3]);
      float inter = fmaxf(xx2 - xx1, 0.f) * fmaxf(yy2 - yy1, 0.f);
      float ai = (sb[i][2] - sb[i][0]) * (sb[i][3] - sb[i][1]);
      float aj = (sb[j][2] - sb[j][0]) * (sb[j][3] - sb[j][1]);
      float iou = inter / (ai + aj - inter + 1e-8f);
      if (iou >= IOU_THR_F) atomicOr(&sup[i][j >> 5], 1u << (j & 31));
    }
  }
  __syncthreads();

  // Greedy scan in one thread over register bitmask (~100 trivial iterations)
  if (tid == 0) {
    unsigned int kw0 = 0, kw1 = 0, kw2 = 0, kw3 = 0;
    for (int k = 0; k < MAXN; k++)
      if (sel[k] >= 0) {
        if (k < 32) kw0 |= 1u << k;
        else if (k < 64) kw1 |= 1u << (k - 32);
        else if (k < 96) kw2 |= 1u << (k - 64);
        else kw3 |= 1u << (k - 96);
      }
    for (int i = 0; i < MAXN; i++) {
      unsigned int bit = (i < 32) ? (kw0 >> i) : (i < 64) ? (kw1 >> (i - 32))
                        : (i < 96) ? (kw2 >> (i - 64)) : (kw3 >> (i - 96));
      if (bit & 1u) {
        kw0 &= ~sup[i][0]; kw1 &= ~sup[i][1];
        kw2 &= ~sup[i][2]; kw3 &= ~sup[i][3];
      }
    }
    keepw[0] = kw0; keepw[1] = kw1; keepw[2] = kw2; keepw[3] = kw3;
  }
  __syncthreads();

  // Write output: dets [B,100,6] then keep [B,100] as 0.0/1.0
  if (tid < MAXN) {
    int k = tid;
    bool kp = (keepw[k >> 5] >> (k & 31)) & 1u;
    float* row = out + ((size_t)b * MAXN + k) * 6;
    if (kp) {
      row[0] = sb[k][0]; row[1] = sb[k][1]; row[2] = sb[k][2]; row[3] = sb[k][3];
      row[4] = ssc[k];   row[5] = (float)slab[k];
    } else {
      row[0] = 0.f; row[1] = 0.f; row[2] = 0.f; row[3] = 0.f;
      row[4] = 0.f; row[5] = -1.f;
    }
    out[(size_t)BB * MAXN * 6 + (size_t)b * MAXN + k] = kp ? 1.0f : 0.0f;
  }
}

extern "C" void kernel_launch(void* const* d_in, const int* in_sizes, int n_in,
                              void* d_out, int out_size, void* d_ws, size_t ws_size,
                              hipStream_t stream) {
  const float* cls    = (const float*)d_in[0];  // [B,N,C]
  const float* bbox   = (const float*)d_in[1];  // [B,N,4]
  const float* obj    = (const float*)d_in[2];  // [B,N]
  const float* priors = (const float*)d_in[3];  // [N,4]
  float* out = (float*)d_out;                   // [B,100,6] ++ [B,100]
  float* masked = (float*)d_ws;                 // [B,N] masked scores (2.15 MB)

  k1_score<<<dim3(K1_GX, BB), 256, 0, stream>>>(cls, obj, masked);
  k2_all<<<BB, K2T, 0, stream>>>(cls, bbox, priors, masked, out);
}